// Round 1
// baseline (840.912 us; speedup 1.0000x reference)
//
#include <hip/hip_runtime.h>
#include <cstdint>
#include <cstddef>

typedef _Float16 f16;
typedef _Float16 f16x8 __attribute__((ext_vector_type(8)));
typedef float f32x4 __attribute__((ext_vector_type(4)));

// ---------------------------------------------------------------------------
// async global->LDS, 16B per lane. LDS dest is wave-uniform base + lane*16.
// ---------------------------------------------------------------------------
__device__ __forceinline__ void async16(const void* g, void* l) {
  __builtin_amdgcn_global_load_lds(
      (const __attribute__((address_space(1))) unsigned int*)g,
      (__attribute__((address_space(3))) unsigned int*)l,
      16, 0, 0);
}

// ---------------------------------------------------------------------------
// Weight prep: Wt[o][i*8+g] = coef[i][o][g] * ssp[i][o]   (Wt is [O][K], K=I*9)
// ---------------------------------------------------------------------------
template <int I, int O>
__global__ void prep_coef(const float* __restrict__ coef,
                          const float* __restrict__ ssp,
                          f16* __restrict__ Wt) {
  int tid = blockIdx.x * 256 + threadIdx.x;
  if (tid >= I * O) return;
  int i = tid / O, o = tid % O;             // o fastest -> coalesced coef reads
  float s = ssp[tid];
  const float* c = coef + (size_t)tid * 8;
  f16x8 out;
#pragma unroll
  for (int g = 0; g < 8; ++g) out[g] = (f16)(c[g] * s);
  *(f16x8*)(Wt + (size_t)o * (I * 9) + (size_t)i * 8) = out;
}

// Wt[o][I*8+i] = sb[i][o]
template <int I, int O>
__global__ void prep_base(const float* __restrict__ sb, f16* __restrict__ Wt) {
  int tid = blockIdx.x * 256 + threadIdx.x;
  if (tid >= I * O) return;
  int o = tid / I, i = tid % I;             // i fastest -> coalesced Wt writes
  Wt[(size_t)o * (I * 9) + (size_t)I * 8 + i] = (f16)sb[(size_t)i * O + o];
}

// ---------------------------------------------------------------------------
// Activation: Act[n][i*8+g] = cubic B-spline basis, Act[n][I*8+i] = silu(x)
// Dense basis slot g of x: M(u), u = 2.5x+5.5-g, M = uniform cubic B-spline
// on [0,4] (piecewise Horner, branchless).
// ---------------------------------------------------------------------------
template <int I>
__global__ void kan_act(const float* __restrict__ X, f16* __restrict__ A,
                        long long total) {
  long long tid = (long long)blockIdx.x * 256 + threadIdx.x;
  if (tid >= total) return;
  int i = (int)(tid % I);
  long long n = tid / I;
  float x = X[tid];
  float v = 2.5f * x + 5.5f;
  f16x8 out;
#pragma unroll
  for (int g = 0; g < 8; ++g) {
    float u = v - (float)g;
    float a  = (u < 1.f) ? (1.f / 6.f) : (u < 2.f) ? -0.5f : (u < 3.f) ? 0.5f : (-1.f / 6.f);
    float bb = (u < 1.f) ? 0.f : (u < 2.f) ? 2.f  : (u < 3.f) ? -4.f : 2.f;
    float cc = (u < 1.f) ? 0.f : (u < 2.f) ? -2.f : (u < 3.f) ? 10.f : -8.f;
    float dd = (u < 1.f) ? 0.f : (u < 2.f) ? (2.f / 3.f) : (u < 3.f) ? (-22.f / 3.f) : (32.f / 3.f);
    float m = ((a * u + bb) * u + cc) * u + dd;
    out[g] = (f16)((u > 0.f && u < 4.f) ? m : 0.f);
  }
  size_t K = (size_t)I * 9;
  *(f16x8*)(A + n * K + (size_t)i * 8) = out;
  float sig = 1.f / (1.f + __expf(-x));
  A[n * K + (size_t)I * 8 + i] = (f16)(x * sig);
}

// ---------------------------------------------------------------------------
// GEMM: C[M,N] = A[M,K] * B[N,K]^T. A row-major [M][K] f16, B row-major [N][K]
// f16 (pre-transposed weights), C f32 [M][N]. 128x128 tile, BK=64,
// mfma_f32_16x16x32_f16, 4 waves * 4x4 accs. global_load_lds width-16 staging.
// ATOMIC=1: atomicAdd epilogue (split-K via blockIdx.z * kChunk).
// ---------------------------------------------------------------------------
template <int ATOMIC>
__global__ __launch_bounds__(256) void gemm16(const f16* __restrict__ A,
                                              const f16* __restrict__ B,
                                              float* __restrict__ C,
                                              int N, int K, int kChunk) {
  __shared__ __align__(16) f16 sA[128 * 64];
  __shared__ __align__(16) f16 sB[128 * 64];
  const int t = threadIdx.x;
  const int n0 = blockIdx.x * 128;
  const int m0 = blockIdx.y * 128;
  const int kBeg = blockIdx.z * kChunk;
  const int kEnd = kBeg + kChunk;
  const int w = t >> 6;
  const int lane = t & 63;
  const int wm = (w >> 1) * 64;
  const int wn = (w & 1) * 64;
  const int lr = lane & 15;
  const int lq = lane >> 4;
  const int wbase = t & 192;                 // w*64, wave-uniform
  const int srow = t >> 3;                   // staging row (q=0)
  const int skof = (t & 7) * 8;              // staging col offset (elements)

  f32x4 acc[4][4] = {};
  const f16* Arow = A + (size_t)(m0 + srow) * K + skof;
  const f16* Brow = B + (size_t)(n0 + srow) * K + skof;

  for (int k0 = kBeg; k0 < kEnd; k0 += 64) {
#pragma unroll
    for (int q = 0; q < 4; ++q) {
      async16(Arow + (size_t)(q * 32) * K + k0, &sA[(q * 256 + wbase) * 8]);
      async16(Brow + (size_t)(q * 32) * K + k0, &sB[(q * 256 + wbase) * 8]);
    }
    __syncthreads();
#pragma unroll
    for (int kk = 0; kk < 64; kk += 32) {
      f16x8 av[4], bv[4];
#pragma unroll
      for (int i = 0; i < 4; ++i)
        av[i] = *(const f16x8*)&sA[(wm + i * 16 + lr) * 64 + kk + lq * 8];
#pragma unroll
      for (int j = 0; j < 4; ++j)
        bv[j] = *(const f16x8*)&sB[(wn + j * 16 + lr) * 64 + kk + lq * 8];
#pragma unroll
      for (int i = 0; i < 4; ++i)
#pragma unroll
        for (int j = 0; j < 4; ++j)
          acc[i][j] = __builtin_amdgcn_mfma_f32_16x16x32_f16(av[i], bv[j],
                                                             acc[i][j], 0, 0, 0);
    }
    __syncthreads();
  }

#pragma unroll
  for (int i = 0; i < 4; ++i) {
#pragma unroll
    for (int j = 0; j < 4; ++j) {
      const int col = n0 + wn + j * 16 + lr;
#pragma unroll
      for (int r = 0; r < 4; ++r) {
        const int row = m0 + wm + i * 16 + lq * 4 + r;
        if (ATOMIC)
          atomicAdd(&C[(size_t)row * N + col], acc[i][j][r]);
        else
          C[(size_t)row * N + col] = acc[i][j][r];
      }
    }
  }
}

// ---------------------------------------------------------------------------
extern "C" void kernel_launch(void* const* d_in, const int* in_sizes, int n_in,
                              void* d_out, int out_size, void* d_ws,
                              size_t ws_size, hipStream_t stream) {
  const float* x     = (const float*)d_in[0];
  const float* coef1 = (const float*)d_in[1];
  const float* sb1   = (const float*)d_in[2];
  const float* ssp1  = (const float*)d_in[3];
  const float* coef2 = (const float*)d_in[4];
  const float* sb2   = (const float*)d_in[5];
  const float* ssp2  = (const float*)d_in[6];

  const int Mtot = 8192;
  const int I1 = 512, O1 = 2048, K1 = I1 * 9;   // 4608
  const int I2 = 2048, O2 = 512, K2 = I2 * 9;   // 18432

  char* ws = (char*)d_ws;
  const size_t szW1 = (size_t)O1 * K1 * sizeof(f16);   // 18.9 MB
  const size_t szW2 = (size_t)O2 * K2 * sizeof(f16);   // 18.9 MB
  const size_t szH  = (size_t)Mtot * O1 * sizeof(float); // 67.1 MB
  f16*   W1  = (f16*)ws;
  f16*   W2  = (f16*)(ws + szW1);
  float* h1  = (float*)(ws + szW1 + szW2);
  f16*   Act = (f16*)(ws + szW1 + szW2 + szH);
  const size_t fixed = szW1 + szW2 + szH;
  if (ws_size <= fixed) return;  // cannot run; fail visibly
  const size_t actBytes = ws_size - fixed;

  auto calcR = [&](int K) -> int {
    size_t rows = actBytes / ((size_t)K * sizeof(f16));
    if (rows > (size_t)Mtot) rows = Mtot;
    return (int)(rows & ~(size_t)127);
  };
  const int R1 = calcR(K1);
  const int R2 = calcR(K2);
  if (R1 < 128 || R2 < 128) return;

  // weight prep
  {
    int n1 = I1 * O1;
    prep_coef<512, 2048><<<(n1 + 255) / 256, 256, 0, stream>>>(coef1, ssp1, W1);
    prep_base<512, 2048><<<(n1 + 255) / 256, 256, 0, stream>>>(sb1, W1);
    int n2 = I2 * O2;
    prep_coef<2048, 512><<<(n2 + 255) / 256, 256, 0, stream>>>(coef2, ssp2, W2);
    prep_base<2048, 512><<<(n2 + 255) / 256, 256, 0, stream>>>(sb2, W2);
  }

  // layer 1: h1 = Act1 @ W1^T
  for (int m0 = 0; m0 < Mtot; m0 += R1) {
    int R = (R1 < Mtot - m0) ? R1 : (Mtot - m0);
    long long tot = (long long)R * I1;
    kan_act<512><<<(int)((tot + 255) / 256), 256, 0, stream>>>(
        x + (size_t)m0 * I1, Act, tot);
    gemm16<0><<<dim3(O1 / 128, R / 128, 1), 256, 0, stream>>>(
        Act, W1, h1 + (size_t)m0 * O1, O1, K1, K1);
  }

  // layer 2: out = Act2 @ W2^T   (split-K=4 with atomic accumulate)
  hipMemsetAsync(d_out, 0, (size_t)Mtot * O2 * sizeof(float), stream);
  for (int m0 = 0; m0 < Mtot; m0 += R2) {
    int R = (R2 < Mtot - m0) ? R2 : (Mtot - m0);
    long long tot = (long long)R * I2;
    kan_act<2048><<<(int)((tot + 255) / 256), 256, 0, stream>>>(
        h1 + (size_t)m0 * I2, Act, tot);
    const int SK = 4;
    gemm16<1><<<dim3(O2 / 128, R / 128, SK), 256, 0, stream>>>(
        Act, W2, (float*)d_out + (size_t)m0 * O2, O2, K2, K2 / SK);
  }
}

// Round 2
// 804.780 us; speedup vs baseline: 1.0449x; 1.0449x over previous
//
#include <hip/hip_runtime.h>
#include <cstdint>
#include <cstddef>

typedef _Float16 f16;
typedef _Float16 f16x8 __attribute__((ext_vector_type(8)));
typedef float f32x4 __attribute__((ext_vector_type(4)));

// ---------------------------------------------------------------------------
// async global->LDS, 16B per lane. LDS dest is wave-uniform base + lane*16.
// ---------------------------------------------------------------------------
__device__ __forceinline__ void async16(const void* g, void* l) {
  __builtin_amdgcn_global_load_lds(
      (const __attribute__((address_space(1))) unsigned int*)g,
      (__attribute__((address_space(3))) unsigned int*)l,
      16, 0, 0);
}

// ---------------------------------------------------------------------------
// Weight prep: Wt[o][i*8+g] = coef[i][o][g] * ssp[i][o]   (Wt is [O][K], K=I*9)
// ---------------------------------------------------------------------------
template <int I, int O>
__global__ void prep_coef(const float* __restrict__ coef,
                          const float* __restrict__ ssp,
                          f16* __restrict__ Wt) {
  int tid = blockIdx.x * 256 + threadIdx.x;
  if (tid >= I * O) return;
  int i = tid / O, o = tid % O;             // o fastest -> coalesced coef reads
  float s = ssp[tid];
  const float* c = coef + (size_t)tid * 8;
  f16x8 out;
#pragma unroll
  for (int g = 0; g < 8; ++g) out[g] = (f16)(c[g] * s);
  *(f16x8*)(Wt + (size_t)o * (I * 9) + (size_t)i * 8) = out;
}

// Wt[o][I*8+i] = sb[i][o]
template <int I, int O>
__global__ void prep_base(const float* __restrict__ sb, f16* __restrict__ Wt) {
  int tid = blockIdx.x * 256 + threadIdx.x;
  if (tid >= I * O) return;
  int o = tid / I, i = tid % I;             // i fastest -> coalesced Wt writes
  Wt[(size_t)o * (I * 9) + (size_t)I * 8 + i] = (f16)sb[(size_t)i * O + o];
}

// ---------------------------------------------------------------------------
// Activation: Act[n][i*8+g] = cubic B-spline basis, Act[n][I*8+i] = silu(x)
// ---------------------------------------------------------------------------
template <int I>
__global__ void kan_act(const float* __restrict__ X, f16* __restrict__ A,
                        long long total) {
  long long tid = (long long)blockIdx.x * 256 + threadIdx.x;
  if (tid >= total) return;
  int i = (int)(tid % I);
  long long n = tid / I;
  float x = X[tid];
  float v = 2.5f * x + 5.5f;
  f16x8 out;
#pragma unroll
  for (int g = 0; g < 8; ++g) {
    float u = v - (float)g;
    float a  = (u < 1.f) ? (1.f / 6.f) : (u < 2.f) ? -0.5f : (u < 3.f) ? 0.5f : (-1.f / 6.f);
    float bb = (u < 1.f) ? 0.f : (u < 2.f) ? 2.f  : (u < 3.f) ? -4.f : 2.f;
    float cc = (u < 1.f) ? 0.f : (u < 2.f) ? -2.f : (u < 3.f) ? 10.f : -8.f;
    float dd = (u < 1.f) ? 0.f : (u < 2.f) ? (2.f / 3.f) : (u < 3.f) ? (-22.f / 3.f) : (32.f / 3.f);
    float m = ((a * u + bb) * u + cc) * u + dd;
    out[g] = (f16)((u > 0.f && u < 4.f) ? m : 0.f);
  }
  size_t K = (size_t)I * 9;
  *(f16x8*)(A + n * K + (size_t)i * 8) = out;
  float sig = 1.f / (1.f + __expf(-x));
  A[n * K + (size_t)I * 8 + i] = (f16)(x * sig);
}

// ---------------------------------------------------------------------------
// GEMM: C[M,N] = A[M,K] * B[N,K]^T. A row-major [M][K] f16, B row-major [N][K]
// f16 (pre-transposed weights), C f32 [M][N]. 128x128 tile, BK=64,
// mfma_f32_16x16x32_f16, 4 waves * 4x4 accs. global_load_lds width-16 staging.
//
// LDS XOR swizzle (16B-chunk granularity): LDS[r][c] holds global chunk
// [r][c ^ (r&7)]. Staging lane (r = t>>3, c = t&7) fetches source chunk
// (t&7)^((t>>3)&7) — constant per lane since (srow+32q)&7 == srow&7.
// Readers index chunk ((kk>>3)+lq) ^ (lr&7): a quad's 16 lanes then spread
// over all 8 chunk positions (2 lanes/bank-group = conflict-free, m136),
// instead of all 16 hitting one 4-bank group (16-way, the R1 3e7 conflicts).
// ---------------------------------------------------------------------------
template <int ATOMIC>
__global__ __launch_bounds__(256) void gemm16(const f16* __restrict__ A,
                                              const f16* __restrict__ B,
                                              float* __restrict__ C,
                                              int N, int K, int kChunk) {
  __shared__ __align__(16) f16 sA[128 * 64];
  __shared__ __align__(16) f16 sB[128 * 64];
  const int t = threadIdx.x;
  const int n0 = blockIdx.x * 128;
  const int m0 = blockIdx.y * 128;
  const int kBeg = blockIdx.z * kChunk;
  const int kEnd = kBeg + kChunk;
  const int w = t >> 6;
  const int lane = t & 63;
  const int wm = (w >> 1) * 64;
  const int wn = (w & 1) * 64;
  const int lr = lane & 15;
  const int lq = lane >> 4;
  const int wbase = t & 192;                 // w*64, wave-uniform
  const int srow = t >> 3;                   // staging row (q=0)
  const int skof = ((t & 7) ^ (srow & 7)) * 8;  // swizzled source col (elems)

  f32x4 acc[4][4] = {};
  const f16* Arow = A + (size_t)(m0 + srow) * K + skof;
  const f16* Brow = B + (size_t)(n0 + srow) * K + skof;

  for (int k0 = kBeg; k0 < kEnd; k0 += 64) {
#pragma unroll
    for (int q = 0; q < 4; ++q) {
      async16(Arow + (size_t)(q * 32) * K + k0, &sA[(q * 256 + wbase) * 8]);
      async16(Brow + (size_t)(q * 32) * K + k0, &sB[(q * 256 + wbase) * 8]);
    }
    __syncthreads();
#pragma unroll
    for (int kk = 0; kk < 64; kk += 32) {
      f16x8 av[4], bv[4];
#pragma unroll
      for (int i = 0; i < 4; ++i) {
        const int ra = wm + i * 16 + lr;
        const int ca = ((kk >> 3) + lq) ^ (ra & 7);
        av[i] = *(const f16x8*)&sA[ra * 64 + ca * 8];
      }
#pragma unroll
      for (int j = 0; j < 4; ++j) {
        const int rb = wn + j * 16 + lr;
        const int cb = ((kk >> 3) + lq) ^ (rb & 7);
        bv[j] = *(const f16x8*)&sB[rb * 64 + cb * 8];
      }
#pragma unroll
      for (int i = 0; i < 4; ++i)
#pragma unroll
        for (int j = 0; j < 4; ++j)
          acc[i][j] = __builtin_amdgcn_mfma_f32_16x16x32_f16(av[i], bv[j],
                                                             acc[i][j], 0, 0, 0);
    }
    __syncthreads();
  }

#pragma unroll
  for (int i = 0; i < 4; ++i) {
#pragma unroll
    for (int j = 0; j < 4; ++j) {
      const int col = n0 + wn + j * 16 + lr;
#pragma unroll
      for (int r = 0; r < 4; ++r) {
        const int row = m0 + wm + i * 16 + lq * 4 + r;
        if (ATOMIC)
          atomicAdd(&C[(size_t)row * N + col], acc[i][j][r]);
        else
          C[(size_t)row * N + col] = acc[i][j][r];
      }
    }
  }
}

// ---------------------------------------------------------------------------
extern "C" void kernel_launch(void* const* d_in, const int* in_sizes, int n_in,
                              void* d_out, int out_size, void* d_ws,
                              size_t ws_size, hipStream_t stream) {
  const float* x     = (const float*)d_in[0];
  const float* coef1 = (const float*)d_in[1];
  const float* sb1   = (const float*)d_in[2];
  const float* ssp1  = (const float*)d_in[3];
  const float* coef2 = (const float*)d_in[4];
  const float* sb2   = (const float*)d_in[5];
  const float* ssp2  = (const float*)d_in[6];

  const int Mtot = 8192;
  const int I1 = 512, O1 = 2048, K1 = I1 * 9;   // 4608
  const int I2 = 2048, O2 = 512, K2 = I2 * 9;   // 18432

  char* ws = (char*)d_ws;
  const size_t szW1 = (size_t)O1 * K1 * sizeof(f16);   // 18.9 MB
  const size_t szW2 = (size_t)O2 * K2 * sizeof(f16);   // 18.9 MB
  const size_t szH  = (size_t)Mtot * O1 * sizeof(float); // 67.1 MB
  f16*   W1  = (f16*)ws;
  f16*   W2  = (f16*)(ws + szW1);
  float* h1  = (float*)(ws + szW1 + szW2);
  f16*   Act = (f16*)(ws + szW1 + szW2 + szH);
  const size_t fixed = szW1 + szW2 + szH;
  if (ws_size <= fixed) return;  // cannot run; fail visibly
  const size_t actBytes = ws_size - fixed;

  auto calcR = [&](int K) -> int {
    size_t rows = actBytes / ((size_t)K * sizeof(f16));
    if (rows > (size_t)Mtot) rows = Mtot;
    return (int)(rows & ~(size_t)127);
  };
  const int R1 = calcR(K1);
  const int R2 = calcR(K2);
  if (R1 < 128 || R2 < 128) return;

  // weight prep
  {
    int n1 = I1 * O1;
    prep_coef<512, 2048><<<(n1 + 255) / 256, 256, 0, stream>>>(coef1, ssp1, W1);
    prep_base<512, 2048><<<(n1 + 255) / 256, 256, 0, stream>>>(sb1, W1);
    int n2 = I2 * O2;
    prep_coef<2048, 512><<<(n2 + 255) / 256, 256, 0, stream>>>(coef2, ssp2, W2);
    prep_base<2048, 512><<<(n2 + 255) / 256, 256, 0, stream>>>(sb2, W2);
  }

  // layer 1: h1 = Act1 @ W1^T
  for (int m0 = 0; m0 < Mtot; m0 += R1) {
    int R = (R1 < Mtot - m0) ? R1 : (Mtot - m0);
    long long tot = (long long)R * I1;
    kan_act<512><<<(int)((tot + 255) / 256), 256, 0, stream>>>(
        x + (size_t)m0 * I1, Act, tot);
    gemm16<0><<<dim3(O1 / 128, R / 128, 1), 256, 0, stream>>>(
        Act, W1, h1 + (size_t)m0 * O1, O1, K1, K1);
  }

  // layer 2: out = Act2 @ W2^T   (split-K=4 with atomic accumulate)
  hipMemsetAsync(d_out, 0, (size_t)Mtot * O2 * sizeof(float), stream);
  for (int m0 = 0; m0 < Mtot; m0 += R2) {
    int R = (R2 < Mtot - m0) ? R2 : (Mtot - m0);
    long long tot = (long long)R * I2;
    kan_act<2048><<<(int)((tot + 255) / 256), 256, 0, stream>>>(
        h1 + (size_t)m0 * I2, Act, tot);
    const int SK = 4;
    gemm16<1><<<dim3(O2 / 128, R / 128, SK), 256, 0, stream>>>(
        Act, W2, (float*)d_out + (size_t)m0 * O2, O2, K2, K2 / SK);
  }
}